// Round 6
// baseline (976.394 us; speedup 1.0000x reference)
//
#include <hip/hip_runtime.h>
#include <math.h>

#define IN_CH 768
#define OUT_CH 48
#define NB 32
#define HW 3136      // 56*56
#define HW4 784      // HW/4
#define NROWS (NB * IN_CH)   // 24576
#define GRID 512
#define RPB (NROWS / GRID)   // 48 rows per block

// clang-native float4 (HIP's float4 is a class; nontemporal builtin needs this)
typedef float f32x4 __attribute__((ext_vector_type(4)));

// Manual grid barrier: all GRID blocks are co-resident by construction
// (512 blocks x 256 thr, ~6.3KB LDS, low VGPR -> capacity >= 2048 blocks).
// Counters zeroed by hipMemsetAsync before launch. Device-scope atomics.
__device__ __forceinline__ void grid_sync(unsigned* bar) {
    __syncthreads();
    if (threadIdx.x == 0) {
        __threadfence();  // make this block's prior global writes device-visible
        __hip_atomic_fetch_add(bar, 1u, __ATOMIC_RELEASE, __HIP_MEMORY_SCOPE_AGENT);
        while (__hip_atomic_load(bar, __ATOMIC_ACQUIRE, __HIP_MEMORY_SCOPE_AGENT) < GRID)
            __builtin_amdgcn_s_sleep(2);
        __threadfence();
    }
    __syncthreads();
}

__global__ __launch_bounds__(256) void fused_kernel(const float* __restrict__ in,
                                                    const float* __restrict__ w1,   // [48,768]
                                                    const float* __restrict__ w2,   // [768,48]
                                                    float* __restrict__ out,
                                                    float* __restrict__ ws) {
    unsigned* bar0 = (unsigned*)ws;        // barrier counters (zeroed host-side)
    unsigned* bar1 = (unsigned*)ws + 32;
    float* avg  = ws + 64;                 // [NROWS]
    float* mx   = avg + NROWS;             // [NROWS]
    float* gate = mx + NROWS;              // [NROWS]

    const int lane = threadIdx.x & 63;
    const int wv   = threadIdx.x >> 6;
    const int base = blockIdx.x * RPB;

    // ---------------- phase 1: fused avg+max pool, wave-per-row ----------------
    for (int r = wv; r < RPB; r += 4) {
        const int row = base + r;
        const f32x4* p = (const f32x4*)(in + (size_t)row * HW);
        float s = 0.f;
        float m = -INFINITY;
        for (int i = lane; i < HW4; i += 64) {
            f32x4 v = p[i];
            s += (v.x + v.y) + (v.z + v.w);
            m = fmaxf(m, fmaxf(fmaxf(v.x, v.y), fmaxf(v.z, v.w)));
        }
        for (int off = 32; off; off >>= 1) {
            s += __shfl_down(s, off);
            m = fmaxf(m, __shfl_down(m, off));
        }
        if (lane == 0) {
            avg[row] = s * (1.0f / (float)HW);
            mx[row]  = m;
        }
    }

    grid_sync(bar0);

    // ---------------- phase 2: tiny MLP + sigmoid (blocks 0..31) ----------------
    // gate[b,c] = sigmoid( (w2 @ (relu(w1@avg_b) + relu(w1@mx_b)))[c] )
    __shared__ float sa[IN_CH], sx[IN_CH], hsum[OUT_CH];
    if (blockIdx.x < NB) {
        const int b = blockIdx.x;
        for (int c = threadIdx.x; c < IN_CH; c += 256) {
            sa[c] = avg[b * IN_CH + c];
            sx[c] = mx[b * IN_CH + c];
        }
        __syncthreads();
        for (int o = wv; o < OUT_CH; o += 4) {
            const float* wrow = w1 + o * IN_CH;
            float pa = 0.f, px = 0.f;
            for (int c = lane; c < IN_CH; c += 64) {
                float w = wrow[c];
                pa += w * sa[c];
                px += w * sx[c];
            }
            for (int off = 32; off; off >>= 1) {
                pa += __shfl_down(pa, off);
                px += __shfl_down(px, off);
            }
            if (lane == 0) hsum[o] = fmaxf(pa, 0.f) + fmaxf(px, 0.f);
        }
        __syncthreads();
        for (int c = threadIdx.x; c < IN_CH; c += 256) {
            const float* wrow = w2 + c * OUT_CH;   // 48 consecutive floats
            float acc = 0.f;
#pragma unroll
            for (int o = 0; o < OUT_CH; ++o) acc += wrow[o] * hsum[o];
            gate[b * IN_CH + c] = 1.0f / (1.0f + expf(-acc));
        }
    }

    grid_sync(bar1);

    // ---------------- phase 3: scale own chunk, reverse order, nt stores ----------------
    for (int r = wv; r < RPB; r += 4) {
        const int row = base + (RPB - 1 - r);
        const float g = gate[row];
        const f32x4* p = (const f32x4*)(in + (size_t)row * HW);
        f32x4* q = (f32x4*)(out + (size_t)row * HW);
        for (int i = lane; i < HW4; i += 64) {
            f32x4 v = p[i];
            v *= g;
            __builtin_nontemporal_store(v, q + i);
        }
    }
}

extern "C" void kernel_launch(void* const* d_in, const int* in_sizes, int n_in,
                              void* d_out, int out_size, void* d_ws, size_t ws_size,
                              hipStream_t stream) {
    const float* in = (const float*)d_in[0];
    const float* w1 = (const float*)d_in[1];
    const float* w2 = (const float*)d_in[2];
    float* out = (float*)d_out;
    float* ws  = (float*)d_ws;

    // zero the barrier counters (first 256 bytes of ws)
    hipMemsetAsync(d_ws, 0, 256, stream);
    fused_kernel<<<GRID, 256, 0, stream>>>(in, w1, w2, out, ws);
}